// Round 2
// 446.244 us; speedup vs baseline: 1.0572x; 1.0572x over previous
//
#include <hip/hip_runtime.h>

#define EPS 1e-8f
#define TAU_INV 10.0f
#define NITER 10

// DPP control codes (gfx9+)
#define DPP_QUAD_XOR1    0xB1   // quad_perm:[1,0,3,2]
#define DPP_QUAD_XOR2    0x4E   // quad_perm:[2,3,0,1]
#define DPP_HALF_MIRROR  0x141  // row_half_mirror: lane l -> 7-l within 8 (== xor7;
                                 //   equals xor4 once values are quad-uniform)
#define DPP_ROW_ROR8     0x128  // row_ror:8 == xor 8 within a 16-lane row

typedef unsigned int uint2v __attribute__((ext_vector_type(2)));

// x + perm(x) with the permutation fused into the add via DPP (VALU pipe).
template <int CTRL>
__device__ __forceinline__ float dpp_add(float x) {
    int xi = __float_as_int(x);
    int pi = __builtin_amdgcn_update_dpp(0, xi, CTRL, 0xF, 0xF, true);
    return x + __int_as_float(pi);
}

// Butterfly stage across lane^16 / lane^32 using gfx950 permlane*_swap.
// The builtin returns BOTH post-swap registers (vdst', vsrc'), so for
// lane<16-group: one holds x[lane], the other x[lane^16]; the sum is the
// butterfly stage on every lane. (Inline-asm version was broken: the
// compiler coalesced the two identical-valued "+v" operands into one reg.)
__device__ __forceinline__ float xor16_add(float x) {
#if __has_builtin(__builtin_amdgcn_permlane16_swap)
    uint2v r = __builtin_amdgcn_permlane16_swap(__float_as_uint(x),
                                                __float_as_uint(x),
                                                false, false);
    return __uint_as_float(r.x) + __uint_as_float(r.y);
#else
    return x + __shfl_xor(x, 16);
#endif
}

__device__ __forceinline__ float xor32_add(float x) {
#if __has_builtin(__builtin_amdgcn_permlane32_swap)
    uint2v r = __builtin_amdgcn_permlane32_swap(__float_as_uint(x),
                                                __float_as_uint(x),
                                                false, false);
    return __uint_as_float(r.x) + __uint_as_float(r.y);
#else
    return x + __shfl_xor(x, 32);
#endif
}

// One wave (64 lanes) per 32x32 matrix. K held in registers as 4 float4 per
// lane: K[j] = row (8j + (lane>>3)), cols 4*(lane&7)..+3. Sinkhorn iterations
// run on scaling vectors a (rows), b (cols); M = diag(a) K diag(b) written once.
// All reductions are VALU-pipe (DPP / permlane_swap) -- no LDS-pipe shuffles.
__global__ __launch_bounds__(256) void
SinkhornProjection_60962765799638_kernel(const float* __restrict__ H,
                                         float* __restrict__ out, int n_mat) {
    const int lane = threadIdx.x & 63;
    const int wv = threadIdx.x >> 6;
    const long long mat = (long long)blockIdx.x * 4 + wv;
    if (mat >= n_mat) return;

    const float* __restrict__ src = H + mat * 1024;
    float* __restrict__ dst = out + mat * 1024;

    float4 K[4];
#pragma unroll
    for (int j = 0; j < 4; ++j)
        K[j] = *reinterpret_cast<const float4*>(src + j * 256 + lane * 4);

    // K = max(exp(H/tau), EPS)
#pragma unroll
    for (int j = 0; j < 4; ++j) {
        K[j].x = fmaxf(__expf(K[j].x * TAU_INV), EPS);
        K[j].y = fmaxf(__expf(K[j].y * TAU_INV), EPS);
        K[j].z = fmaxf(__expf(K[j].z * TAU_INV), EPS);
        K[j].w = fmaxf(__expf(K[j].w * TAU_INV), EPS);
    }

    float a[4] = {1.f, 1.f, 1.f, 1.f};          // a[j] for row 8j + (lane>>3)
    float4 b = make_float4(1.f, 1.f, 1.f, 1.f); // b for cols 4*(lane&7)..+3

#pragma unroll
    for (int it = 0; it < NITER; ++it) {
        // ---- row normalize: a <- a / (a*(K b) + EPS) ----
        // reduce across lane bits {0,1,2} (the 8 col-groups)
        float s[4];
#pragma unroll
        for (int t = 0; t < 4; ++t) {
            float v = fmaf(K[t].x, b.x,
                      fmaf(K[t].y, b.y,
                      fmaf(K[t].z, b.z, K[t].w * b.w)));
            v = dpp_add<DPP_QUAD_XOR1>(v);   // xor 1
            v = dpp_add<DPP_QUAD_XOR2>(v);   // xor 2
            v = dpp_add<DPP_HALF_MIRROR>(v); // xor 4 (quads uniform by now)
            s[t] = v;
        }
#pragma unroll
        for (int t = 0; t < 4; ++t)
            a[t] = a[t] * __builtin_amdgcn_rcpf(fmaf(a[t], s[t], EPS));

        // ---- col normalize: b <- b / (b*(K^T a) + EPS) ----
        // reduce across lane bits {3,4,5} (the 8 row-groups)
        float4 p;
        p.x = fmaf(a[0], K[0].x, fmaf(a[1], K[1].x, fmaf(a[2], K[2].x, a[3] * K[3].x)));
        p.y = fmaf(a[0], K[0].y, fmaf(a[1], K[1].y, fmaf(a[2], K[2].y, a[3] * K[3].y)));
        p.z = fmaf(a[0], K[0].z, fmaf(a[1], K[1].z, fmaf(a[2], K[2].z, a[3] * K[3].z)));
        p.w = fmaf(a[0], K[0].w, fmaf(a[1], K[1].w, fmaf(a[2], K[2].w, a[3] * K[3].w)));

        p.x = dpp_add<DPP_ROW_ROR8>(p.x);    // xor 8
        p.y = dpp_add<DPP_ROW_ROR8>(p.y);
        p.z = dpp_add<DPP_ROW_ROR8>(p.z);
        p.w = dpp_add<DPP_ROW_ROR8>(p.w);
        p.x = xor16_add(p.x);                // xor 16
        p.y = xor16_add(p.y);
        p.z = xor16_add(p.z);
        p.w = xor16_add(p.w);
        p.x = xor32_add(p.x);                // xor 32
        p.y = xor32_add(p.y);
        p.z = xor32_add(p.z);
        p.w = xor32_add(p.w);

        b.x = b.x * __builtin_amdgcn_rcpf(fmaf(b.x, p.x, EPS));
        b.y = b.y * __builtin_amdgcn_rcpf(fmaf(b.y, p.y, EPS));
        b.z = b.z * __builtin_amdgcn_rcpf(fmaf(b.z, p.z, EPS));
        b.w = b.w * __builtin_amdgcn_rcpf(fmaf(b.w, p.w, EPS));
    }

    // ---- write M = a * K * b, same coalesced layout as the load ----
#pragma unroll
    for (int j = 0; j < 4; ++j) {
        float4 m;
        m.x = a[j] * K[j].x * b.x;
        m.y = a[j] * K[j].y * b.y;
        m.z = a[j] * K[j].z * b.z;
        m.w = a[j] * K[j].w * b.w;
        *reinterpret_cast<float4*>(dst + j * 256 + lane * 4) = m;
    }
}

extern "C" void kernel_launch(void* const* d_in, const int* in_sizes, int n_in,
                              void* d_out, int out_size, void* d_ws, size_t ws_size,
                              hipStream_t stream) {
    const float* H = (const float*)d_in[0];
    float* out = (float*)d_out;
    const int n_mat = in_sizes[0] / 1024;
    const int blocks = (n_mat + 3) / 4;
    hipLaunchKernelGGL(SinkhornProjection_60962765799638_kernel,
                       dim3(blocks), dim3(256), 0, stream, H, out, n_mat);
}

// Round 3
// 432.274 us; speedup vs baseline: 1.0914x; 1.0323x over previous
//
#include <hip/hip_runtime.h>

#define EPS 1e-8f
#define TAU_INV 10.0f
#define NITER 10

// DPP control codes (gfx9+)
#define DPP_QUAD_XOR1    0xB1   // quad_perm:[1,0,3,2]
#define DPP_QUAD_XOR2    0x4E   // quad_perm:[2,3,0,1]
#define DPP_HALF_MIRROR  0x141  // row_half_mirror: lane l -> 7-l within 8 (== xor7;
                                 //   equals xor4 once values are quad-uniform)
#define DPP_ROW_ROR8     0x128  // row_ror:8 == xor 8 within a 16-lane row

typedef float f32x2 __attribute__((ext_vector_type(2)));
typedef unsigned int uint2v __attribute__((ext_vector_type(2)));

// x + perm(x) with the permutation fused into the add via DPP (VALU pipe).
template <int CTRL>
__device__ __forceinline__ float dpp_add(float x) {
    int xi = __float_as_int(x);
    int pi = __builtin_amdgcn_update_dpp(0, xi, CTRL, 0xF, 0xF, true);
    return x + __int_as_float(pi);
}

// Butterfly stage across lane^16 / lane^32 via gfx950 permlane*_swap builtins
// (returns BOTH post-swap registers; their sum is the butterfly on every lane).
__device__ __forceinline__ float xor16_add(float x) {
#if __has_builtin(__builtin_amdgcn_permlane16_swap)
    uint2v r = __builtin_amdgcn_permlane16_swap(__float_as_uint(x),
                                                __float_as_uint(x),
                                                false, false);
    return __uint_as_float(r.x) + __uint_as_float(r.y);
#else
    return x + __shfl_xor(x, 16);
#endif
}

__device__ __forceinline__ float xor32_add(float x) {
#if __has_builtin(__builtin_amdgcn_permlane32_swap)
    uint2v r = __builtin_amdgcn_permlane32_swap(__float_as_uint(x),
                                                __float_as_uint(x),
                                                false, false);
    return __uint_as_float(r.x) + __uint_as_float(r.y);
#else
    return x + __shfl_xor(x, 32);
#endif
}

__device__ __forceinline__ f32x2 splat2(float v) {
    f32x2 r; r.x = v; r.y = v; return r;
}

// Packed fma on float2 -> v_pk_fma_f32 (VOP3P, 2 floats/inst).
__device__ __forceinline__ f32x2 fma2(f32x2 a, f32x2 b, f32x2 c) {
#if __has_builtin(__builtin_elementwise_fma)
    return __builtin_elementwise_fma(a, b, c);
#else
    return a * b + c;
#endif
}

__device__ __forceinline__ f32x2 max2(f32x2 a, f32x2 b) {
#if __has_builtin(__builtin_elementwise_max)
    return __builtin_elementwise_max(a, b);
#else
    f32x2 r; r.x = fmaxf(a.x, b.x); r.y = fmaxf(a.y, b.y); return r;
#endif
}

// One wave (64 lanes) per 32x32 matrix. K held in registers as 4x(2xfloat2)
// per lane: row (8j + (lane>>3)), cols 4*(lane&7)..+3. Sinkhorn in scaling
// form: a <- 1/(K b), b <- 1/(K^T a)  (the a/(a*s+eps) form collapses exactly
// to 1/s since eps=1e-8 is negligible vs O(1) sums). M = diag(a) K diag(b)
// written once. Reductions all VALU-pipe (DPP / permlane_swap); matvecs use
// packed v_pk_fma_f32.
__global__ __launch_bounds__(256) void
SinkhornProjection_60962765799638_kernel(const float* __restrict__ H,
                                         float* __restrict__ out, int n_mat) {
    const int lane = threadIdx.x & 63;
    const int wv = threadIdx.x >> 6;
    const long long mat = (long long)blockIdx.x * 4 + wv;
    if (mat >= n_mat) return;

    const float* __restrict__ src = H + mat * 1024;
    float* __restrict__ dst = out + mat * 1024;

    float4 raw[4];
#pragma unroll
    for (int j = 0; j < 4; ++j)
        raw[j] = *reinterpret_cast<const float4*>(src + j * 256 + lane * 4);

    // K = max(exp(H/tau), EPS); halves kept as float2 for packed math
    f32x2 Klo[4], Khi[4];
    const f32x2 veps = splat2(EPS);
#pragma unroll
    for (int j = 0; j < 4; ++j) {
        f32x2 lo, hi;
        lo.x = raw[j].x; lo.y = raw[j].y;
        hi.x = raw[j].z; hi.y = raw[j].w;
        lo = lo * splat2(TAU_INV);   // v_pk_mul_f32
        hi = hi * splat2(TAU_INV);
        lo.x = __expf(lo.x); lo.y = __expf(lo.y);   // v_exp_f32 (scalar-only pipe)
        hi.x = __expf(hi.x); hi.y = __expf(hi.y);
        Klo[j] = max2(lo, veps);     // v_pk_max_f32
        Khi[j] = max2(hi, veps);
    }

    float a[4] = {1.f, 1.f, 1.f, 1.f};  // a[j] for row 8j + (lane>>3)
    f32x2 blo = splat2(1.f);            // b for cols 4*(lane&7) + 0,1
    f32x2 bhi = splat2(1.f);            // b for cols 4*(lane&7) + 2,3

#pragma unroll
    for (int it = 0; it < NITER; ++it) {
        // ---- row step: a <- 1 / rowsum(K diag(b)) ----
        // reduce across lane bits {0,1,2} (the 8 col-groups)
#pragma unroll
        for (int t = 0; t < 4; ++t) {
            f32x2 v2 = fma2(Khi[t], bhi, Klo[t] * blo);  // pk_mul + pk_fma
            float v = v2.x + v2.y;
            v = dpp_add<DPP_QUAD_XOR1>(v);   // xor 1
            v = dpp_add<DPP_QUAD_XOR2>(v);   // xor 2
            v = dpp_add<DPP_HALF_MIRROR>(v); // xor 4 (quads uniform by now)
            a[t] = __builtin_amdgcn_rcpf(v);
        }

        // ---- col step: b <- 1 / colsum(diag(a) K) ----
        // reduce across lane bits {3,4,5} (the 8 row-groups)
        f32x2 plo = fma2(splat2(a[0]), Klo[0],
                    fma2(splat2(a[1]), Klo[1],
                    fma2(splat2(a[2]), Klo[2], splat2(a[3]) * Klo[3])));
        f32x2 phi = fma2(splat2(a[0]), Khi[0],
                    fma2(splat2(a[1]), Khi[1],
                    fma2(splat2(a[2]), Khi[2], splat2(a[3]) * Khi[3])));

        float p0 = plo.x, p1 = plo.y, p2 = phi.x, p3 = phi.y;
        p0 = dpp_add<DPP_ROW_ROR8>(p0);  // xor 8
        p1 = dpp_add<DPP_ROW_ROR8>(p1);
        p2 = dpp_add<DPP_ROW_ROR8>(p2);
        p3 = dpp_add<DPP_ROW_ROR8>(p3);
        p0 = xor16_add(p0);              // xor 16
        p1 = xor16_add(p1);
        p2 = xor16_add(p2);
        p3 = xor16_add(p3);
        p0 = xor32_add(p0);              // xor 32
        p1 = xor32_add(p1);
        p2 = xor32_add(p2);
        p3 = xor32_add(p3);

        blo.x = __builtin_amdgcn_rcpf(p0);
        blo.y = __builtin_amdgcn_rcpf(p1);
        bhi.x = __builtin_amdgcn_rcpf(p2);
        bhi.y = __builtin_amdgcn_rcpf(p3);
    }

    // ---- write M = a * K * b, same coalesced layout as the load ----
#pragma unroll
    for (int j = 0; j < 4; ++j) {
        f32x2 mlo = splat2(a[j]) * (Klo[j] * blo);  // 2x v_pk_mul_f32
        f32x2 mhi = splat2(a[j]) * (Khi[j] * bhi);
        float4 m;
        m.x = mlo.x; m.y = mlo.y; m.z = mhi.x; m.w = mhi.y;
        *reinterpret_cast<float4*>(dst + j * 256 + lane * 4) = m;
    }
}

extern "C" void kernel_launch(void* const* d_in, const int* in_sizes, int n_in,
                              void* d_out, int out_size, void* d_ws, size_t ws_size,
                              hipStream_t stream) {
    const float* H = (const float*)d_in[0];
    float* out = (float*)d_out;
    const int n_mat = in_sizes[0] / 1024;
    const int blocks = (n_mat + 3) / 4;
    hipLaunchKernelGGL(SinkhornProjection_60962765799638_kernel,
                       dim3(blocks), dim3(256), 0, stream, H, out, n_mat);
}